// Round 10
// baseline (111.509 us; speedup 1.0000x reference)
//
#include <hip/hip_runtime.h>

// NeuralRodriguesOperator: B=512, C_L=64, C_J=16, 4x4 matrices.
// R10: wave = 64m x 64n (acc 4x4) -> af[4] amortized over 4 bf frags.
// R9 pipe model: LDS-return was binding (af reused for only 2 bf; 10.5us
// floor vs MFMA 8.5us), and measured ~31us -> stall-dominated. Now per
// wave-chunk: 4 ds_read_b128 + 4 coalesced global b128 + 16 pk_mul + 16
// MFMA -> MFMA-bound (1241 cy/SIMD MFMA vs 753 cy LDS vs ~340 VALU per
// round). Block = 8 waves (2x4) covering 128m x 256n; Fs 128 rows = 67.6KB
// -> 2 blocks/CU, 16 waves/CU, 4/SIMD. Grid 16 zs x 16 m-tiles = 256 blocks
// (exactly co-resident). launch_bounds(512,4) pins VGPR<=128.
// Poison-floor note (R9): harness restore+256MiB ws poison sits in the
// timed window (~45us floor we cannot touch); controllable = prep+gemm+
// reduce+gaps.
//   trig[b,c'] = (1, cos th, sin th), k = c'*256 + i*4 + q, K=8448
//   C1[(b,p),(j,r)]: (trig*Fv0) x B1t;  C2[(b,r),(j,p)]: (trig*Fv1) x B2t
//   out = C1 + C2 via reduce kernel (verified R6-R9).

#define NRO_B   512
#define NRO_CL  64
#define K_DIM   8448          // 33 * 256 ; 264 chunks of 32
#define M_DIM   2048
#define N_DIM   256
#define SK      8
#define B_ELems  ((size_t)N_DIM * K_DIM)       // per matrix (fp16), chunk-tiled
#define FV_ELems ((size_t)M_DIM * N_DIM)       // per matrix (fp16)
#define P_ELems  ((size_t)2 * SK * M_DIM * N_DIM)  // fp32 partials

typedef __attribute__((ext_vector_type(8))) _Float16 half8;
typedef __attribute__((ext_vector_type(4))) _Float16 half4_t;
typedef __attribute__((ext_vector_type(4))) float floatx4;

__device__ __forceinline__ void load16(const float* p, float w[4][4]) {
    const float4* p4 = (const float4*)p;
    #pragma unroll
    for (int a = 0; a < 4; ++a) {
        float4 x = p4[a];
        w[a][0] = x.x; w[a][1] = x.y; w[a][2] = x.z; w[a][3] = x.w;
    }
}

__device__ __forceinline__ half8 scale8(half8 v, _Float16 s) {
    half8 r;
    #pragma unroll
    for (int x = 0; x < 8; ++x) r[x] = v[x] * s;   // -> v_pk_mul_f16 x4
    return r;
}

// ---------------- prep: blocks [0,128) Fv, [128,640) B [verified R9] ----------------
// B element (n, k) lives at Bd[(g*256 + n)*32 + (k&31)], g = k>>5.
__global__ __launch_bounds__(256) void nro_prep(
    const float* __restrict__ F_in,
    const float* __restrict__ W_bias, const float* __restrict__ W_cos,
    const float* __restrict__ W_sin,  const float* __restrict__ Wb_bias,
    const float* __restrict__ Wb_cos, const float* __restrict__ Wb_sin,
    _Float16* __restrict__ Bbuf,              // [2][264][256][32]
    _Float16* __restrict__ Fv)                // [2][2048][256]
{
    const int w = threadIdx.x >> 6, i = threadIdx.x & 63;
    if (blockIdx.x < 128) {
        const int b = blockIdx.x * 4 + w;     // 0..511
        float f[4][4];
        load16(F_in + ((size_t)b * 64 + i) * 16, f);
        #pragma unroll
        for (int a = 0; a < 4; ++a) {
            half4_t v0 = { (_Float16)f[a][0], (_Float16)f[a][1],
                           (_Float16)f[a][2], (_Float16)f[a][3] };
            *(half4_t*)(Fv + (size_t)(b * 4 + a) * 256 + i * 4) = v0;
            half4_t v1 = { (_Float16)f[0][a], (_Float16)f[1][a],
                           (_Float16)f[2][a], (_Float16)f[3][a] };
            *(half4_t*)(Fv + FV_ELems + (size_t)(b * 4 + a) * 256 + i * 4) = v1;
        }
    } else {
        const int unit = (blockIdx.x - 128) * 4 + w;   // 0..2047
        const int j = unit >> 5, c = (unit >> 1) & 15, h = unit & 1;
        _Float16* Bd = Bbuf + (size_t)h * B_ELems;
        const size_t wbase = (((size_t)(j * 64 + i)) * 16 + c) * 16;

        float wc4[4][4], ws4[4][4];
        if (h == 0) { load16(W_cos  + wbase, wc4); load16(W_sin  + wbase, ws4); }
        else        { load16(Wb_cos + wbase, wc4); load16(Wb_sin + wbase, ws4); }

        // k = c'*256 + i*4 + q  ->  g = c'*8 + (i>>3), kin = (i&7)*4 + q
        const int gc  = (1 + c)  * 8 + (i >> 3);
        const int gs  = (17 + c) * 8 + (i >> 3);
        const int kin = (i & 7) * 4;
        #pragma unroll
        for (int a = 0; a < 4; ++a) {
            const int n = j * 4 + a;
            half4_t vc, vs;
            if (h == 0) {   // B1[(j,r=a)][..q] = W[q][a]
                vc = (half4_t){ (_Float16)wc4[0][a], (_Float16)wc4[1][a],
                                (_Float16)wc4[2][a], (_Float16)wc4[3][a] };
                vs = (half4_t){ (_Float16)ws4[0][a], (_Float16)ws4[1][a],
                                (_Float16)ws4[2][a], (_Float16)ws4[3][a] };
            } else {        // B2[(j,p=a)][..q] = Wb[a][q]
                vc = (half4_t){ (_Float16)wc4[a][0], (_Float16)wc4[a][1],
                                (_Float16)wc4[a][2], (_Float16)wc4[a][3] };
                vs = (half4_t){ (_Float16)ws4[a][0], (_Float16)ws4[a][1],
                                (_Float16)ws4[a][2], (_Float16)ws4[a][3] };
            }
            *(half4_t*)(Bd + ((size_t)gc * 256 + n) * 32 + kin) = vc;
            *(half4_t*)(Bd + ((size_t)gs * 256 + n) * 32 + kin) = vs;
        }
        if (c == 0) {       // c'=0 bias: g = i>>3
            float t[4][4];
            load16(((h == 0) ? W_bias : Wb_bias) + ((size_t)(j * 64 + i)) * 16, t);
            #pragma unroll
            for (int a = 0; a < 4; ++a) {
                half4_t v;
                if (h == 0) v = (half4_t){ (_Float16)t[0][a], (_Float16)t[1][a],
                                           (_Float16)t[2][a], (_Float16)t[3][a] };
                else        v = (half4_t){ (_Float16)t[a][0], (_Float16)t[a][1],
                                           (_Float16)t[a][2], (_Float16)t[a][3] };
                *(half4_t*)(Bd + ((size_t)(i >> 3) * 256 + (j * 4 + a)) * 32 + kin) = v;
            }
        }
    }
}

// ---------------- GEMM: 512 thr = 8 waves (2m x 4n), wave 64m x 64n ----------------
// grid.x = zs (16): z=zs>>3, sk=zs&7; grid.y = m-tile of 128 (16).
__global__ __launch_bounds__(512, 4) void nro_gemm(
    const _Float16* __restrict__ Bbuf, const _Float16* __restrict__ Fv,
    const float* __restrict__ theta,
    float* __restrict__ part)                 // [16][2048][256] fp32
{
    const int zs = blockIdx.x;                // 0..15
    const int z  = zs >> 3;
    const int sk = zs & 7;
    const int m0 = blockIdx.y * 128;

    const _Float16* Bm = Bbuf + (size_t)z * B_ELems;
    const _Float16* Fm = Fv + (size_t)z * FV_ELems + (size_t)m0 * 256;

    __shared__ _Float16 Fs[128 * 264];        // 128 rows padded +8 halfs (67.6 KB)
    __shared__ float    trig[32 * 34];        // [b_local][c'] (c'=0 -> 1.0)

    const int tid  = threadIdx.x;
    const int lane = tid & 63;
    const int w    = tid >> 6;                // wave 0..7
    const int wm   = (w >> 2) * 64;           // wave m-base (0/64)
    const int wn   = (w & 3) * 64;            // wave n-base (0/64/128/192)

    // ---- stage Fs + trig, once ----
    #pragma unroll
    for (int kk = 0; kk < 8; ++kk) {
        const int idx = kk * 512 + tid;       // 4096 half8-chunks
        const int row = idx >> 5, cf = idx & 31;
        half8 v = *(const half8*)(Fm + (size_t)row * 256 + cf * 8);
        *(half8*)(Fs + row * 264 + cf * 8) = v;
    }
    {
        const int bl = tid >> 4, c = tid & 15;          // 32 b x 16 c
        const float th = theta[(m0 >> 2) * 16 + tid];   // theta[b0+bl][c]
        trig[bl * 34 + 1 + c]  = __cosf(th);
        trig[bl * 34 + 17 + c] = __sinf(th);
        if (c == 0) trig[bl * 34] = 1.0f;
    }
    __syncthreads();                           // the ONLY barrier

    const int fr = lane & 15, fq8 = (lane >> 4) * 8;

    // Chunk-tiled B: lane addresses ascend contiguously -> coalesced 1KB/frag.
    const _Float16* Brow[4];
    #pragma unroll
    for (int t = 0; t < 4; ++t)
        Brow[t] = Bm + (size_t)(wn + t * 16 + fr) * 32 + fq8;

    floatx4 acc[4][4] = {};
    _Float16 tv[4] = {};

    int g = sk * 33;                           // global k-chunk index
    for (int kt = 0; kt < 33; ++kt, ++g) {
        const int cp  = g >> 3;                // c' (fixed within chunk)
        const int iq0 = (g & 7) * 32;          // column window in Fs
        if (kt == 0 || (g & 7) == 0) {         // uniform branch: c' changed
            #pragma unroll
            for (int t = 0; t < 4; ++t)
                tv[t] = (_Float16)trig[((wm >> 2) + t * 4 + (fr >> 2)) * 34 + cp];
        }
        half8 bf[4];
        #pragma unroll
        for (int t = 0; t < 4; ++t)
            bf[t] = *(const half8*)(Brow[t] + (size_t)g * 8192);
        half8 af[4];
        #pragma unroll
        for (int t = 0; t < 4; ++t) {
            half8 fvf = *(const half8*)(Fs + (wm + t * 16 + fr) * 264 + iq0 + fq8);
            af[t] = scale8(fvf, tv[t]);        // A = trig * Fv
        }
        #pragma unroll
        for (int mt = 0; mt < 4; ++mt)
            #pragma unroll
            for (int nt = 0; nt < 4; ++nt)
                acc[mt][nt] = __builtin_amdgcn_mfma_f32_16x16x32_f16(
                    af[mt], bf[nt], acc[mt][nt], 0, 0, 0);
    }

    // C row m=(lane>>4)*4+e, col n=lane&15 [verified R5-R9]
    const int col = lane & 15, row4 = (lane >> 4) * 4;
    #pragma unroll
    for (int mt = 0; mt < 4; ++mt)
        #pragma unroll
        for (int nt = 0; nt < 4; ++nt)
            #pragma unroll
            for (int e = 0; e < 4; ++e) {
                const int m = m0 + wm + mt * 16 + row4 + e;
                const int n = wn + nt * 16 + col;
                part[((size_t)zs * M_DIM + m) * N_DIM + n] = acc[mt][nt][e];
            }
}

// ---------------- reduce: sum 16 partials, apply permutation [verified R6-R9] ----------------
__global__ __launch_bounds__(256) void nro_reduce(
    const float* __restrict__ part, float* __restrict__ out)
{
    const int t = blockIdx.x * 256 + threadIdx.x;   // 131072
    const int b = t >> 8;
    const int j = (t >> 2) & 63;
    const int p = t & 3;

    float4 o = make_float4(0.f, 0.f, 0.f, 0.f);
    #pragma unroll
    for (int sk = 0; sk < SK; ++sk) {
        const float4 c1 = *(const float4*)(
            part + ((size_t)sk * M_DIM + b * 4 + p) * N_DIM + j * 4);
        o.x += c1.x; o.y += c1.y; o.z += c1.z; o.w += c1.w;
        const float* p2 = part + ((size_t)(SK + sk) * M_DIM + b * 4) * N_DIM + j * 4 + p;
        o.x += p2[0 * N_DIM]; o.y += p2[1 * N_DIM];
        o.z += p2[2 * N_DIM]; o.w += p2[3 * N_DIM];
    }
    *(float4*)(out + ((size_t)(b * 64 + j) * 16 + p * 4)) = o;
}

// ---------------- fallback (R4 fp32 path, verified) ----------------
__global__ __launch_bounds__(256, 2) void nro_fallback(
    const float* __restrict__ F_in, const float* __restrict__ theta,
    const float* __restrict__ W_bias, const float* __restrict__ W_cos,
    const float* __restrict__ W_sin,  const float* __restrict__ Wb_bias,
    const float* __restrict__ Wb_cos, const float* __restrict__ Wb_sin,
    float* __restrict__ out)
{
    __shared__ float smem[8448];
    const int j      = blockIdx.x >> 3;
    const int isplit = blockIdx.x & 7;
    const int i0     = isplit * 8;
    const int lane   = threadIdx.x & 63;
    const int chunk  = __builtin_amdgcn_readfirstlane(threadIdx.x >> 6);
    const int b      = blockIdx.y * 64 + lane;
    const int tid    = threadIdx.x;
    {
        float4* s4 = (float4*)smem;
        const int base16  = (j * 64 + i0) * 16;
        const int base256 = (j * 64 + i0) * 256;
        if (tid < 32)      s4[tid] = ((const float4*)(W_bias + base16))[tid];
        else if (tid < 64) s4[tid] = ((const float4*)(Wb_bias + base16))[tid - 32];
        #pragma unroll
        for (int r = 0; r < 2; ++r) {
            const int k = r * 256 + tid;
            s4[64 + k]   = ((const float4*)(W_cos  + base256))[k];
            s4[576 + k]  = ((const float4*)(W_sin  + base256))[k];
            s4[1088 + k] = ((const float4*)(Wb_cos + base256))[k];
            s4[1600 + k] = ((const float4*)(Wb_sin + base256))[k];
        }
    }
    float csc[16], css[16];
    #pragma unroll
    for (int c = 0; c < 16; ++c) {
        float t = theta[b * 16 + c];
        csc[c] = __cosf(t); css[c] = __sinf(t);
    }
    __syncthreads();
    float acc[16];
    #pragma unroll
    for (int e = 0; e < 16; ++e) acc[e] = 0.0f;
    #pragma unroll
    for (int ii = 0; ii < 2; ++ii) {
        const int il = chunk * 2 + ii;
        const int i  = i0 + il;
        float f[16];
        const float4* fp = (const float4*)(F_in + (b * 64 + i) * 16);
        #pragma unroll
        for (int v = 0; v < 4; ++v) {
            float4 x = fp[v];
            f[v*4+0]=x.x; f[v*4+1]=x.y; f[v*4+2]=x.z; f[v*4+3]=x.w;
        }
        const float* wb  = smem + il * 16;
        const float* wbb = smem + 128  + il * 16;
        const float* wc  = smem + 256  + il * 256;
        const float* wsn = smem + 2304 + il * 256;
        const float* wbc = smem + 4352 + il * 256;
        const float* wbs = smem + 6400 + il * 256;
        float U[16], Ub[16];
        #pragma unroll
        for (int e = 0; e < 16; ++e) { U[e] = wb[e]; Ub[e] = wbb[e]; }
        #pragma unroll 4
        for (int c = 0; c < 16; ++c) {
            const float cc = csc[c], ss = css[c];
            #pragma unroll
            for (int e = 0; e < 16; ++e) {
                U[e]  = fmaf(wc [c*16+e], cc, U[e]);
                U[e]  = fmaf(wsn[c*16+e], ss, U[e]);
                Ub[e] = fmaf(wbc[c*16+e], cc, Ub[e]);
                Ub[e] = fmaf(wbs[c*16+e], ss, Ub[e]);
            }
        }
        #pragma unroll
        for (int p = 0; p < 4; ++p)
            #pragma unroll
            for (int r = 0; r < 4; ++r) {
                float a = acc[p*4+r];
                #pragma unroll
                for (int q = 0; q < 4; ++q) {
                    a = fmaf(f[p*4+q],  U[q*4+r], a);
                    a = fmaf(Ub[p*4+q], f[q*4+r], a);
                }
                acc[p*4+r] = a;
            }
    }
    __syncthreads();
    if (chunk > 0) {
        float* r = smem + (chunk - 1) * 1088 + lane * 17;
        #pragma unroll
        for (int e = 0; e < 16; ++e) r[e] = acc[e];
    }
    __syncthreads();
    if (chunk == 0) {
        #pragma unroll
        for (int cc = 0; cc < 3; ++cc) {
            const float* r = smem + cc * 1088 + lane * 17;
            #pragma unroll
            for (int e = 0; e < 16; ++e) acc[e] += r[e];
        }
        float* o = out + ((size_t)b * 64 + j) * 16;
        #pragma unroll
        for (int e = 0; e < 16; ++e) atomicAdd(o + e, acc[e]);
    }
}

extern "C" void kernel_launch(void* const* d_in, const int* in_sizes, int n_in,
                              void* d_out, int out_size, void* d_ws, size_t ws_size,
                              hipStream_t stream) {
    const float* F_in    = (const float*)d_in[0];
    const float* theta   = (const float*)d_in[1];
    const float* W_bias  = (const float*)d_in[2];
    const float* W_cos   = (const float*)d_in[3];
    const float* W_sin   = (const float*)d_in[4];
    const float* Wb_bias = (const float*)d_in[5];
    const float* Wb_cos  = (const float*)d_in[6];
    const float* Wb_sin  = (const float*)d_in[7];
    float* out = (float*)d_out;

    const size_t needB  = 2 * B_ELems  * sizeof(_Float16);  // 8.65 MB
    const size_t needFv = 2 * FV_ELems * sizeof(_Float16);  // 2.10 MB
    const size_t needP  = P_ELems * sizeof(float);          // 33.55 MB
    if (ws_size >= needB + needFv + needP) {
        _Float16* Bbuf = (_Float16*)d_ws;
        _Float16* Fv   = (_Float16*)((char*)d_ws + needB);
        float*    part = (float*)((char*)d_ws + needB + needFv);
        nro_prep<<<640, 256, 0, stream>>>(F_in, W_bias, W_cos, W_sin,
                                          Wb_bias, Wb_cos, Wb_sin, Bbuf, Fv);
        nro_gemm<<<dim3(16, 16), 512, 0, stream>>>(Bbuf, Fv, theta, part);
        nro_reduce<<<512, 256, 0, stream>>>(part, out);
    } else {
        hipMemsetAsync(out, 0, (size_t)out_size * sizeof(float), stream);
        dim3 grid(64 * 8, 512 / 64, 1);
        nro_fallback<<<grid, 256, 0, stream>>>(
            F_in, theta, W_bias, W_cos, W_sin, Wb_bias, Wb_cos, Wb_sin, out);
    }
}

// Round 12
// 110.224 us; speedup vs baseline: 1.0117x; 1.0117x over previous
//
#include <hip/hip_runtime.h>

// NeuralRodriguesOperator: B=512, C_L=64, C_J=16, 4x4 matrices.
// R12: R10's 3-launch structure (cooperative launch FAILED under graph
// capture in R11 — output never written; harness tripwire confirmed) with
// R11's distance-2 chunk-pair software pipeline in the GEMM K-loop:
// while MFMA-ing chunks (g,g+1) from registers, the coalesced loads for
// (g+2,g+3) are in flight (~2 chunk-rounds of issue cover vs L2 latency).
// R10 post-mortem: GEMM ~31us is B-load-latency bound (pipe floors ~10us;
// R9 vs R10 neutrality ruled out LDS-return and af-reuse as binding).
// GEMM config: 512 blocks x 256 thr = 4 waves of 64m x 64n (af-reuse 4),
// Fs 64 rows padded +8 (33.8KB LDS), grid (16 zs, 32 m-tiles): flat%16=zs
// -> same-B blocks share an XCD.
//   trig[b,c'] = (1, cos th, sin th), k = c'*256 + i*4 + q, K=8448
//   C1[(b,p),(j,r)]: (trig*Fv0) x B1t;  C2[(b,r),(j,p)]: (trig*Fv1) x B2t
//   out = C1 + C2 via reduce kernel (verified R6-R10).
// B chunk-tiled [g][n][32] (verified R9): wave frag load = contiguous 1KB.
// Budget note (R9/R10): ~45us harness ws-poison + restore sits inside the
// timed window; controllable = prep (~9) + GEMM + reduce (~6) + gaps (~20).

#define NRO_B   512
#define NRO_CL  64
#define K_DIM   8448          // 33 * 256 ; 264 chunks of 32
#define M_DIM   2048
#define N_DIM   256
#define SK      8
#define B_ELems  ((size_t)N_DIM * K_DIM)       // per matrix (fp16), chunk-tiled
#define FV_ELems ((size_t)M_DIM * N_DIM)       // per matrix (fp16)
#define P_ELems  ((size_t)2 * SK * M_DIM * N_DIM)  // fp32 partials

typedef __attribute__((ext_vector_type(8))) _Float16 half8;
typedef __attribute__((ext_vector_type(4))) _Float16 half4_t;
typedef __attribute__((ext_vector_type(4))) float floatx4;

__device__ __forceinline__ void load16(const float* p, float w[4][4]) {
    const float4* p4 = (const float4*)p;
    #pragma unroll
    for (int a = 0; a < 4; ++a) {
        float4 x = p4[a];
        w[a][0] = x.x; w[a][1] = x.y; w[a][2] = x.z; w[a][3] = x.w;
    }
}

__device__ __forceinline__ half8 scale8(half8 v, _Float16 s) {
    half8 r;
    #pragma unroll
    for (int x = 0; x < 8; ++x) r[x] = v[x] * s;   // -> v_pk_mul_f16 x4
    return r;
}

// ---------------- prep: blocks [0,128) Fv, [128,640) B [verified R9/R10] ----------------
// B element (n, k) lives at Bd[(g*256 + n)*32 + (k&31)], g = k>>5.
__global__ __launch_bounds__(256) void nro_prep(
    const float* __restrict__ F_in,
    const float* __restrict__ W_bias, const float* __restrict__ W_cos,
    const float* __restrict__ W_sin,  const float* __restrict__ Wb_bias,
    const float* __restrict__ Wb_cos, const float* __restrict__ Wb_sin,
    _Float16* __restrict__ Bbuf,              // [2][264][256][32]
    _Float16* __restrict__ Fv)                // [2][2048][256]
{
    const int w = threadIdx.x >> 6, i = threadIdx.x & 63;
    if (blockIdx.x < 128) {
        const int b = blockIdx.x * 4 + w;     // 0..511
        float f[4][4];
        load16(F_in + ((size_t)b * 64 + i) * 16, f);
        #pragma unroll
        for (int a = 0; a < 4; ++a) {
            half4_t v0 = { (_Float16)f[a][0], (_Float16)f[a][1],
                           (_Float16)f[a][2], (_Float16)f[a][3] };
            *(half4_t*)(Fv + (size_t)(b * 4 + a) * 256 + i * 4) = v0;
            half4_t v1 = { (_Float16)f[0][a], (_Float16)f[1][a],
                           (_Float16)f[2][a], (_Float16)f[3][a] };
            *(half4_t*)(Fv + FV_ELems + (size_t)(b * 4 + a) * 256 + i * 4) = v1;
        }
    } else {
        const int unit = (blockIdx.x - 128) * 4 + w;   // 0..2047
        const int j = unit >> 5, c = (unit >> 1) & 15, h = unit & 1;
        _Float16* Bd = Bbuf + (size_t)h * B_ELems;
        const size_t wbase = (((size_t)(j * 64 + i)) * 16 + c) * 16;

        float wc4[4][4], ws4[4][4];
        if (h == 0) { load16(W_cos  + wbase, wc4); load16(W_sin  + wbase, ws4); }
        else        { load16(Wb_cos + wbase, wc4); load16(Wb_sin + wbase, ws4); }

        // k = c'*256 + i*4 + q  ->  g = c'*8 + (i>>3), kin = (i&7)*4 + q
        const int gc  = (1 + c)  * 8 + (i >> 3);
        const int gs  = (17 + c) * 8 + (i >> 3);
        const int kin = (i & 7) * 4;
        #pragma unroll
        for (int a = 0; a < 4; ++a) {
            const int n = j * 4 + a;
            half4_t vc, vs;
            if (h == 0) {   // B1[(j,r=a)][..q] = W[q][a]
                vc = (half4_t){ (_Float16)wc4[0][a], (_Float16)wc4[1][a],
                                (_Float16)wc4[2][a], (_Float16)wc4[3][a] };
                vs = (half4_t){ (_Float16)ws4[0][a], (_Float16)ws4[1][a],
                                (_Float16)ws4[2][a], (_Float16)ws4[3][a] };
            } else {        // B2[(j,p=a)][..q] = Wb[a][q]
                vc = (half4_t){ (_Float16)wc4[a][0], (_Float16)wc4[a][1],
                                (_Float16)wc4[a][2], (_Float16)wc4[a][3] };
                vs = (half4_t){ (_Float16)ws4[a][0], (_Float16)ws4[a][1],
                                (_Float16)ws4[a][2], (_Float16)ws4[a][3] };
            }
            *(half4_t*)(Bd + ((size_t)gc * 256 + n) * 32 + kin) = vc;
            *(half4_t*)(Bd + ((size_t)gs * 256 + n) * 32 + kin) = vs;
        }
        if (c == 0) {       // c'=0 bias: g = i>>3
            float t[4][4];
            load16(((h == 0) ? W_bias : Wb_bias) + ((size_t)(j * 64 + i)) * 16, t);
            #pragma unroll
            for (int a = 0; a < 4; ++a) {
                half4_t v;
                if (h == 0) v = (half4_t){ (_Float16)t[0][a], (_Float16)t[1][a],
                                           (_Float16)t[2][a], (_Float16)t[3][a] };
                else        v = (half4_t){ (_Float16)t[a][0], (_Float16)t[a][1],
                                           (_Float16)t[a][2], (_Float16)t[a][3] };
                *(half4_t*)(Bd + ((size_t)(i >> 3) * 256 + (j * 4 + a)) * 32 + kin) = v;
            }
        }
    }
}

// ---------------- GEMM: 256 thr = 4 waves of 64m x 64n, pipelined K-loop ----------------
// grid.x = zs (16): z=zs>>3, sk=zs&7; grid.y = m-tile of 64 (32).
__global__ __launch_bounds__(256, 2) void nro_gemm(
    const _Float16* __restrict__ Bbuf, const _Float16* __restrict__ Fv,
    const float* __restrict__ theta,
    float* __restrict__ part)                 // [16][2048][256] fp32
{
    const int zs = blockIdx.x;                // 0..15
    const int z  = zs >> 3;
    const int sk = zs & 7;
    const int m0 = blockIdx.y * 64;

    const _Float16* Bm = Bbuf + (size_t)z * B_ELems;
    const _Float16* Fm = Fv + (size_t)z * FV_ELems + (size_t)m0 * 256;

    __shared__ _Float16 Fs[64 * 264];         // rows padded +8 halfs (33.8 KB)
    __shared__ float    trig[16 * 34];        // [b_local][c'] (c'=0 -> 1.0)

    const int tid  = threadIdx.x;
    const int lane = tid & 63;
    const int w    = tid >> 6;                // wave 0..3
    const int wn   = w * 64;                  // wave n-base

    // ---- stage Fs + trig, once ----
    #pragma unroll
    for (int kk = 0; kk < 8; ++kk) {
        const int idx = kk * 256 + tid;       // 2048 half8-chunks
        const int row = idx >> 5, cf = idx & 31;
        half8 v = *(const half8*)(Fm + (size_t)row * 256 + cf * 8);
        *(half8*)(Fs + row * 264 + cf * 8) = v;
    }
    {
        const int bl = tid >> 4, c = tid & 15;
        const float th = theta[(m0 >> 2) * 16 + tid];   // theta[b0+bl][c]
        trig[bl * 34 + 1 + c]  = __cosf(th);
        trig[bl * 34 + 17 + c] = __sinf(th);
        if (c == 0) trig[bl * 34] = 1.0f;
    }
    __syncthreads();                           // the ONLY barrier

    const int fr = lane & 15, fq8 = (lane >> 4) * 8;

    // Chunk-tiled B: lane addresses ascend contiguously -> coalesced 1KB/frag.
    const _Float16* Brow[4];
    #pragma unroll
    for (int t = 0; t < 4; ++t)
        Brow[t] = Bm + (size_t)(wn + t * 16 + fr) * 32 + fq8;

    floatx4 acc[4][4] = {};
    _Float16 tv[4] = {};
    int cp_last = -1;

    const int base = sk * 33;                  // chunks base .. base+32
    half8 q0[4], q1[4];
    #pragma unroll
    for (int t = 0; t < 4; ++t) {
        q0[t] = *(const half8*)(Brow[t] + (size_t)(base + 0) * 8192);
        q1[t] = *(const half8*)(Brow[t] + (size_t)(base + 1) * 8192);
    }

    #define NRO_CHUNK(GABS, QREG)                                             \
        {                                                                     \
            const int cp_ = (GABS) >> 3;                                      \
            if (cp_ != cp_last) {                                             \
                cp_last = cp_;                                                \
                _Pragma("unroll")                                             \
                for (int t = 0; t < 4; ++t)                                   \
                    tv[t] = (_Float16)trig[(t * 4 + (fr >> 2)) * 34 + cp_];   \
            }                                                                 \
            const int iq0_ = ((GABS) & 7) * 32;                               \
            half8 af[4];                                                      \
            _Pragma("unroll")                                                 \
            for (int t = 0; t < 4; ++t) {                                     \
                half8 fvf = *(const half8*)(Fs + (t * 16 + fr) * 264          \
                                            + iq0_ + fq8);                    \
                af[t] = scale8(fvf, tv[t]);                                   \
            }                                                                 \
            _Pragma("unroll")                                                 \
            for (int mt = 0; mt < 4; ++mt)                                    \
                _Pragma("unroll")                                             \
                for (int nt = 0; nt < 4; ++nt)                                \
                    acc[mt][nt] = __builtin_amdgcn_mfma_f32_16x16x32_f16(     \
                        af[mt], QREG[nt], acc[mt][nt], 0, 0, 0);              \
        }

    for (int it = 0; it < 16; ++it) {
        const int c0 = base + 2 * it;
        // prefetch (c0+2, c0+3): in flight while we MFMA (c0, c0+1)
        half8 p0[4], p1[4];
        #pragma unroll
        for (int t = 0; t < 4; ++t)
            p0[t] = *(const half8*)(Brow[t] + (size_t)(c0 + 2) * 8192);
        if (it < 15) {
            #pragma unroll
            for (int t = 0; t < 4; ++t)
                p1[t] = *(const half8*)(Brow[t] + (size_t)(c0 + 3) * 8192);
        }
        NRO_CHUNK(c0, q0);
        NRO_CHUNK(c0 + 1, q1);
        #pragma unroll
        for (int t = 0; t < 4; ++t) q0[t] = p0[t];
        if (it < 15) {
            #pragma unroll
            for (int t = 0; t < 4; ++t) q1[t] = p1[t];
        }
    }
    NRO_CHUNK(base + 32, q0);                  // tail chunk (33rd)
    #undef NRO_CHUNK

    // partial stores: C row m=(lane>>4)*4+e, col n=lane&15 [verified R5-R10]
    const int col = lane & 15, row4 = (lane >> 4) * 4;
    #pragma unroll
    for (int mt = 0; mt < 4; ++mt)
        #pragma unroll
        for (int nt = 0; nt < 4; ++nt)
            #pragma unroll
            for (int e = 0; e < 4; ++e) {
                const int m = m0 + mt * 16 + row4 + e;
                const int n = wn + nt * 16 + col;
                part[((size_t)zs * M_DIM + m) * N_DIM + n] = acc[mt][nt][e];
            }
}

// ---------------- reduce: sum 16 partials, apply permutation [verified R6-R10] ----------------
__global__ __launch_bounds__(256) void nro_reduce(
    const float* __restrict__ part, float* __restrict__ out)
{
    const int t = blockIdx.x * 256 + threadIdx.x;   // 131072
    const int b = t >> 8;
    const int j = (t >> 2) & 63;
    const int p = t & 3;

    float4 o = make_float4(0.f, 0.f, 0.f, 0.f);
    #pragma unroll
    for (int sk = 0; sk < SK; ++sk) {
        const float4 c1 = *(const float4*)(
            part + ((size_t)sk * M_DIM + b * 4 + p) * N_DIM + j * 4);
        o.x += c1.x; o.y += c1.y; o.z += c1.z; o.w += c1.w;
        const float* p2 = part + ((size_t)(SK + sk) * M_DIM + b * 4) * N_DIM + j * 4 + p;
        o.x += p2[0 * N_DIM]; o.y += p2[1 * N_DIM];
        o.z += p2[2 * N_DIM]; o.w += p2[3 * N_DIM];
    }
    *(float4*)(out + ((size_t)(b * 64 + j) * 16 + p * 4)) = o;
}

// ---------------- fallback (R4 fp32 path, verified) ----------------
__global__ __launch_bounds__(256, 2) void nro_fallback(
    const float* __restrict__ F_in, const float* __restrict__ theta,
    const float* __restrict__ W_bias, const float* __restrict__ W_cos,
    const float* __restrict__ W_sin,  const float* __restrict__ Wb_bias,
    const float* __restrict__ Wb_cos, const float* __restrict__ Wb_sin,
    float* __restrict__ out)
{
    __shared__ float smem[8448];
    const int j      = blockIdx.x >> 3;
    const int isplit = blockIdx.x & 7;
    const int i0     = isplit * 8;
    const int lane   = threadIdx.x & 63;
    const int chunk  = __builtin_amdgcn_readfirstlane(threadIdx.x >> 6);
    const int b      = blockIdx.y * 64 + lane;
    const int tid    = threadIdx.x;
    {
        float4* s4 = (float4*)smem;
        const int base16  = (j * 64 + i0) * 16;
        const int base256 = (j * 64 + i0) * 256;
        if (tid < 32)      s4[tid] = ((const float4*)(W_bias + base16))[tid];
        else if (tid < 64) s4[tid] = ((const float4*)(Wb_bias + base16))[tid - 32];
        #pragma unroll
        for (int r = 0; r < 2; ++r) {
            const int k = r * 256 + tid;
            s4[64 + k]   = ((const float4*)(W_cos  + base256))[k];
            s4[576 + k]  = ((const float4*)(W_sin  + base256))[k];
            s4[1088 + k] = ((const float4*)(Wb_cos + base256))[k];
            s4[1600 + k] = ((const float4*)(Wb_sin + base256))[k];
        }
    }
    float csc[16], css[16];
    #pragma unroll
    for (int c = 0; c < 16; ++c) {
        float t = theta[b * 16 + c];
        csc[c] = __cosf(t); css[c] = __sinf(t);
    }
    __syncthreads();
    float acc[16];
    #pragma unroll
    for (int e = 0; e < 16; ++e) acc[e] = 0.0f;
    #pragma unroll
    for (int ii = 0; ii < 2; ++ii) {
        const int il = chunk * 2 + ii;
        const int i  = i0 + il;
        float f[16];
        const float4* fp = (const float4*)(F_in + (b * 64 + i) * 16);
        #pragma unroll
        for (int v = 0; v < 4; ++v) {
            float4 x = fp[v];
            f[v*4+0]=x.x; f[v*4+1]=x.y; f[v*4+2]=x.z; f[v*4+3]=x.w;
        }
        const float* wb  = smem + il * 16;
        const float* wbb = smem + 128  + il * 16;
        const float* wc  = smem + 256  + il * 256;
        const float* wsn = smem + 2304 + il * 256;
        const float* wbc = smem + 4352 + il * 256;
        const float* wbs = smem + 6400 + il * 256;
        float U[16], Ub[16];
        #pragma unroll
        for (int e = 0; e < 16; ++e) { U[e] = wb[e]; Ub[e] = wbb[e]; }
        #pragma unroll 4
        for (int c = 0; c < 16; ++c) {
            const float cc = csc[c], ss = css[c];
            #pragma unroll
            for (int e = 0; e < 16; ++e) {
                U[e]  = fmaf(wc [c*16+e], cc, U[e]);
                U[e]  = fmaf(wsn[c*16+e], ss, U[e]);
                Ub[e] = fmaf(wbc[c*16+e], cc, Ub[e]);
                Ub[e] = fmaf(wbs[c*16+e], ss, Ub[e]);
            }
        }
        #pragma unroll
        for (int p = 0; p < 4; ++p)
            #pragma unroll
            for (int r = 0; r < 4; ++r) {
                float a = acc[p*4+r];
                #pragma unroll
                for (int q = 0; q < 4; ++q) {
                    a = fmaf(f[p*4+q],  U[q*4+r], a);
                    a = fmaf(Ub[p*4+q], f[q*4+r], a);
                }
                acc[p*4+r] = a;
            }
    }
    __syncthreads();
    if (chunk > 0) {
        float* r = smem + (chunk - 1) * 1088 + lane * 17;
        #pragma unroll
        for (int e = 0; e < 16; ++e) r[e] = acc[e];
    }
    __syncthreads();
    if (chunk == 0) {
        #pragma unroll
        for (int cc = 0; cc < 3; ++cc) {
            const float* r = smem + cc * 1088 + lane * 17;
            #pragma unroll
            for (int e = 0; e < 16; ++e) acc[e] += r[e];
        }
        float* o = out + ((size_t)b * 64 + j) * 16;
        #pragma unroll
        for (int e = 0; e < 16; ++e) atomicAdd(o + e, acc[e]);
    }
}

extern "C" void kernel_launch(void* const* d_in, const int* in_sizes, int n_in,
                              void* d_out, int out_size, void* d_ws, size_t ws_size,
                              hipStream_t stream) {
    const float* F_in    = (const float*)d_in[0];
    const float* theta   = (const float*)d_in[1];
    const float* W_bias  = (const float*)d_in[2];
    const float* W_cos   = (const float*)d_in[3];
    const float* W_sin   = (const float*)d_in[4];
    const float* Wb_bias = (const float*)d_in[5];
    const float* Wb_cos  = (const float*)d_in[6];
    const float* Wb_sin  = (const float*)d_in[7];
    float* out = (float*)d_out;

    const size_t needB  = 2 * B_ELems  * sizeof(_Float16);  // 8.65 MB
    const size_t needFv = 2 * FV_ELems * sizeof(_Float16);  // 2.10 MB
    const size_t needP  = P_ELems * sizeof(float);          // 33.55 MB
    if (ws_size >= needB + needFv + needP) {
        _Float16* Bbuf = (_Float16*)d_ws;
        _Float16* Fv   = (_Float16*)((char*)d_ws + needB);
        float*    part = (float*)((char*)d_ws + needB + needFv);
        nro_prep<<<640, 256, 0, stream>>>(F_in, W_bias, W_cos, W_sin,
                                          Wb_bias, Wb_cos, Wb_sin, Bbuf, Fv);
        nro_gemm<<<dim3(16, 32), 256, 0, stream>>>(Bbuf, Fv, theta, part);
        nro_reduce<<<512, 256, 0, stream>>>(part, out);
    } else {
        hipMemsetAsync(out, 0, (size_t)out_size * sizeof(float), stream);
        dim3 grid(64 * 8, 512 / 64, 1);
        nro_fallback<<<grid, 256, 0, stream>>>(
            F_in, theta, W_bias, W_cos, W_sin, Wb_bias, Wb_cos, Wb_sin, out);
    }
}